// Round 14
// baseline (35.048 us; speedup 1.0000x reference)
//
#include <hip/hip_runtime.h>
#include <hip/hip_bf16.h>
#include <math.h>

#define BB 32
#define SS 256
#define DD 128
#define KK 16
#define VV 50000
#define SK (SS*KK)     // 4096
#define LOG2E 1.44269504f
#define LN2   0.69314718f

typedef __attribute__((ext_vector_type(8))) short bf16x8;
typedef __attribute__((ext_vector_type(4))) short bf16x4;
typedef __attribute__((ext_vector_type(4))) float f32x4;
typedef __attribute__((ext_vector_type(16))) float f32x16;
typedef unsigned short ushort_t;

static __device__ __forceinline__ short f2bf(float f) {
    __hip_bfloat16 h = __float2bfloat16(f);
    return *(short*)&h;
}

static __device__ __forceinline__ float fast_exp2(float x) {
    float r; asm("v_exp_f32 %0, %1" : "=v"(r) : "v"(x)); return r;
}
static __device__ __forceinline__ float fast_log2(float x) {
    float r; asm("v_log_f32 %0, %1" : "=v"(r) : "v"(x)); return r;
}

// byte offset of (row, d[bf16 index]) in a [R][128] bf16 LDS tile, XOR-swizzled
// on 16B chunks: q -> q ^ (row & 15). Conflict-free on b128 frag reads
// (R10/R11 measured SQ_LDS_BANK_CONFLICT == 0 with this layout).
static __device__ __forceinline__ int lds_off(int row, int d) {
    return row * 256 + ((d * 2) ^ ((row & 15) << 4));
}

static __device__ __forceinline__ void gload_lds16(const void* g, void* lds) {
    __builtin_amdgcn_global_load_lds(
        (const __attribute__((address_space(1))) unsigned int*)g,
        (__attribute__((address_space(3))) unsigned int*)lds, 16, 0, 0);
}

#define NLAT (BB*SS*DD)       // 1,048,576
#define NCHUNK_LAT (NLAT/8)   // 131,072

// ---------------- K1: latent fp32 -> bf16 * LOG2E ---------------------------
__global__ __launch_bounds__(256)
void convert_lat_kernel(const float* __restrict__ latent,
                        ushort_t* __restrict__ ws_lat)
{
    int i = blockIdx.x * 256 + threadIdx.x;
    if (i >= NCHUNK_LAT) return;
    const float* src = latent + (size_t)i * 8;
    float f[8];
    *(f32x4*)(f + 0) = ((const f32x4*)src)[0];
    *(f32x4*)(f + 4) = ((const f32x4*)src)[1];
    short o[8];
    #pragma unroll
    for (int e = 0; e < 8; ++e) o[e] = f2bf(f[e] * LOG2E);
    *(bf16x8*)(ws_lat + (size_t)i * 8) = *(bf16x8*)o;
}

// ---------------- K2: main, coalesced-gather version ------------------------
// grid (32 nt, 32 b) = 1024 blocks; 4 waves; LDS 64 KB -> 2 blocks/CU + queue.
// B: each wave's 32 cand rows loaded COALESCED (32 lanes span one row's 512 B;
// 1 instr = 2 full rows), converted bf16, redistributed via swizzled LDS tile.
// A: latent m-half (128 rows, 32 KB) via global_load_lds; staged twice.
__global__ __launch_bounds__(256, 2)
void neg_loss_main(const ushort_t* __restrict__ lat_bf,  // [B,S,D] bf16*log2e
                   const int*   __restrict__ labels,     // [B,S]
                   const int*   __restrict__ samples,    // [B,S*(K-1)]
                   const float* __restrict__ embed,      // [V,D] fp32
                   float* __restrict__ out)              // [B,S,S]
{
    __shared__ char ldsA[128 * 256];   // 32 KB: latent m-half
    __shared__ char ldsB[128 * 256];   // 32 KB: candidate rows (bf16)

    const int nt   = blockIdx.x;
    const int b    = blockIdx.y;
    const int n0   = nt * 128;
    const int tid  = threadIdx.x;
    const int wave = tid >> 6;
    const int lane = tid & 63;
    const int q    = lane & 15;
    const int sub  = lane >> 4;
    const int l31  = lane & 31;
    const int hi   = lane >> 5;

    // ---- idx for this lane's "own" cand row (row = wave*32 + l31) ----
    const int gc  = n0 + wave * 32 + l31;
    const int j   = gc >> 4;
    const int k   = gc & 15;
    const int idx_mine = (k < 15)
        ? samples[(size_t)b * (SS * (KK - 1)) + j * (KK - 1) + k]
        : labels[b * SS + j];

    // ---- coalesced B gather: instr t covers rows (2t | 2t+1) fully ----
    // lane (l31, hi): row wave*32 + 2t + hi, fp32 elements [4*l31, 4*l31+4)
    f32x4 fb[16];
    #pragma unroll
    for (int t = 0; t < 16; ++t) {
        const int idx_t = __shfl(idx_mine, 2 * t + hi);
        fb[t] = *(const f32x4*)(embed + (size_t)idx_t * DD + l31 * 4);
    }

    // ---- stage A (m-half 0): 128 rows via DMA, pre-swizzled source ----
    #pragma unroll
    for (int t = 0; t < 8; ++t) {
        const int r0 = wave * 32 + t * 4;
        const int r  = r0 + sub;
        const ushort_t* src = lat_bf + ((size_t)(b * SS + r) * DD)
                                     + ((q ^ (r & 15)) << 3);
        gload_lds16(src, ldsA + r0 * 256);
    }

    // ---- convert fb -> bf16, redistribute into swizzled ldsB ----
    // lane holds 8 logical bytes [8*l31, 8*l31+8) of row (wave*32 + 2t + hi)
    #pragma unroll
    for (int t = 0; t < 16; ++t) {
        const int row = wave * 32 + 2 * t + hi;
        short o[4];
        #pragma unroll
        for (int e = 0; e < 4; ++e) o[e] = f2bf(fb[t][e]);
        *(bf16x4*)(ldsB + row * 256 + ((l31 * 8) ^ ((row & 15) << 4)))
            = *(bf16x4*)o;
    }

    __syncthreads();   // A(mh0) drained, B tile complete

    const int jcol = nt * 8 + wave * 2 + hi;   // this lane's output column

    #pragma unroll
    for (int mh = 0; mh < 2; ++mh) {
        if (mh == 1) {
            __syncthreads();   // all reads of A(mh0) done
            #pragma unroll
            for (int t = 0; t < 8; ++t) {
                const int r0 = wave * 32 + t * 4;
                const int r  = r0 + sub;
                const ushort_t* src = lat_bf
                    + ((size_t)(b * SS + 128 + r) * DD)
                    + ((q ^ (r & 15)) << 3);
                gload_lds16(src, ldsA + r0 * 256);
            }
            __syncthreads();   // A(mh1) drained
        }

        // ---- MFMA 32x32x16, swapped: D[row=cand][col=lat(scaled)] ----
        const int rB = wave * 32 + l31;   // this lane's cand row (av source)
        f32x16 acc[2][2] = {};
        #pragma unroll
        for (int ks = 0; ks < 8; ++ks) {
            const int d = ks * 16 + hi * 8;
            bf16x8 av = *(const bf16x8*)(ldsB + lds_off(rB, d));
            #pragma unroll
            for (int mt = 0; mt < 2; ++mt) {
                bf16x8 bv0 = *(const bf16x8*)(ldsA + lds_off(mt * 64 + l31, d));
                bf16x8 bv1 = *(const bf16x8*)(ldsA + lds_off(mt * 64 + 32 + l31, d));
                acc[mt][0] = __builtin_amdgcn_mfma_f32_32x32x16_bf16(av, bv0, acc[mt][0], 0, 0, 0);
                acc[mt][1] = __builtin_amdgcn_mfma_f32_32x32x16_bf16(av, bv1, acc[mt][1], 0, 0, 0);
            }
        }

        // ---- fused LSE (base-2), direct per-lane stores ----
        // D rows/lane: (reg&3)+8*(reg>>2)+4*hi; group0 = regs0-7, group1 = 8-15.
        #pragma unroll
        for (int mt = 0; mt < 2; ++mt) {
            #pragma unroll
            for (int f = 0; f < 2; ++f) {
                const f32x16 v = acc[mt][f];
                float pm0 = fmaxf(fmaxf(fmaxf(v[0], v[1]), fmaxf(v[2], v[3])),
                                  fmaxf(fmaxf(v[4], v[5]), fmaxf(v[6], v[7])));
                float pm1 = fmaxf(fmaxf(fmaxf(v[8], v[9]), fmaxf(v[10], v[11])),
                                  fmaxf(fmaxf(v[12], v[13]), fmaxf(v[14], v[15])));
                float om0 = fmaxf(pm0, __shfl_xor(pm0, 32));
                float om1 = fmaxf(pm1, __shfl_xor(pm1, 32));
                float e0 = ((fast_exp2(v[0] - om0) + fast_exp2(v[1] - om0))
                          + (fast_exp2(v[2] - om0) + fast_exp2(v[3] - om0)))
                         + ((fast_exp2(v[4] - om0) + fast_exp2(v[5] - om0))
                          + (fast_exp2(v[6] - om0) + fast_exp2(v[7] - om0)));
                float e1 = ((fast_exp2(v[8]  - om1) + fast_exp2(v[9]  - om1))
                          + (fast_exp2(v[10] - om1) + fast_exp2(v[11] - om1)))
                         + ((fast_exp2(v[12] - om1) + fast_exp2(v[13] - om1))
                          + (fast_exp2(v[14] - om1) + fast_exp2(v[15] - om1)));
                float s0 = e0 + __shfl_xor(e0, 32);
                float s1 = e1 + __shfl_xor(e1, 32);
                float pos0 = __shfl_xor(v[7], 32);  // hi=0 lanes get cand row 15
                float pos1 = v[15];                 // hi=1 lanes hold cand row 31
                const float pos = hi ? pos1 : pos0;
                const float om  = hi ? om1  : om0;
                const float s   = hi ? s1   : s0;
                const int i = mh * 128 + mt * 64 + f * 32 + l31;
                out[((size_t)b * SS + i) * SS + jcol]
                    = (pos - om - fast_log2(s)) * LN2;
            }
        }
    }
}

// ---------------- fallback: R11-style fused kernel (no ws) ------------------
__global__ __launch_bounds__(256, 2)
void neg_loss_fused(const float* __restrict__ latent,
                    const int*   __restrict__ labels,
                    const int*   __restrict__ samples,
                    const float* __restrict__ embed,
                    float* __restrict__ out)
{
    __shared__ char  ldsA[SS * 256];
    __shared__ float trans[256][9];

    const int p     = blockIdx.x;
    const int b     = p >> 4;
    const int npair = p & 15;
    const int tid   = threadIdx.x;
    const int wave  = tid >> 6;
    const int lane  = tid & 63;
    const int l31   = lane & 31;
    const int hi    = lane >> 5;

    const int rB  = wave * 32 + l31;
    const int gc0 = (npair * 2) * 128 + rB;
    const int gc1 = gc0 + 128;
    const int j0i = gc0 >> 4, k0i = gc0 & 15;
    const int j1i = gc1 >> 4, k1i = gc1 & 15;
    const int idx0 = (k0i < 15)
        ? samples[(size_t)b * (SS * (KK - 1)) + j0i * (KK - 1) + k0i]
        : labels[b * SS + j0i];
    const int idx1 = (k1i < 15)
        ? samples[(size_t)b * (SS * (KK - 1)) + j1i * (KK - 1) + k1i]
        : labels[b * SS + j1i];

    f32x4 fbA[16];
    {
        const float* rowp = embed + (size_t)idx0 * DD + hi * 8;
        #pragma unroll
        for (int ks = 0; ks < 8; ++ks) {
            fbA[2 * ks]     = *(const f32x4*)(rowp + ks * 16);
            fbA[2 * ks + 1] = *(const f32x4*)(rowp + ks * 16 + 4);
        }
    }

    #pragma unroll
    for (int pr = 0; pr < 4; ++pr) {
        const int r  = pr * 64 + (tid >> 2);
        const int d0 = (tid & 3) * 32;
        const float* src = latent + ((size_t)b * SS + r) * DD + d0;
        f32x4 f[8];
        #pragma unroll
        for (int c = 0; c < 8; ++c) f[c] = *(const f32x4*)(src + 4 * c);
        short o[32];
        #pragma unroll
        for (int c = 0; c < 8; ++c)
            #pragma unroll
            for (int e = 0; e < 4; ++e)
                o[4 * c + e] = f2bf(f[c][e] * LOG2E);
        #pragma unroll
        for (int c = 0; c < 4; ++c)
            *(bf16x8*)(ldsA + lds_off(r, d0 + 8 * c)) = *(bf16x8*)(o + 8 * c);
    }

    __syncthreads();

    f32x4 fbB[16];
    {
        const float* rowp = embed + (size_t)idx1 * DD + hi * 8;
        #pragma unroll
        for (int ks = 0; ks < 8; ++ks) {
            fbB[2 * ks]     = *(const f32x4*)(rowp + ks * 16);
            fbB[2 * ks + 1] = *(const f32x4*)(rowp + ks * 16 + 4);
        }
    }

    #pragma unroll
    for (int t = 0; t < 2; ++t) {
        const int tile_n = npair * 2 + t;
        const int jc     = wave * 2 + hi;

        bf16x8 av[8];
        #pragma unroll
        for (int ks = 0; ks < 8; ++ks) {
            const f32x4 lo  = t ? fbB[2 * ks]     : fbA[2 * ks];
            const f32x4 hi4 = t ? fbB[2 * ks + 1] : fbA[2 * ks + 1];
            short t8[8];
            #pragma unroll
            for (int e = 0; e < 4; ++e) t8[e]     = f2bf(lo[e]);
            #pragma unroll
            for (int e = 0; e < 4; ++e) t8[4 + e] = f2bf(hi4[e]);
            av[ks] = *(bf16x8*)t8;
        }

        f32x16 acc[4][2] = {};
        #pragma unroll
        for (int ks = 0; ks < 8; ++ks) {
            const int d = ks * 16 + hi * 8;
            #pragma unroll
            for (int mt = 0; mt < 4; ++mt) {
                bf16x8 bv0 = *(const bf16x8*)(ldsA + lds_off(mt * 64 + l31, d));
                bf16x8 bv1 = *(const bf16x8*)(ldsA + lds_off(mt * 64 + 32 + l31, d));
                acc[mt][0] = __builtin_amdgcn_mfma_f32_32x32x16_bf16(av[ks], bv0, acc[mt][0], 0, 0, 0);
                acc[mt][1] = __builtin_amdgcn_mfma_f32_32x32x16_bf16(av[ks], bv1, acc[mt][1], 0, 0, 0);
            }
        }

        #pragma unroll
        for (int mt = 0; mt < 4; ++mt) {
            #pragma unroll
            for (int f = 0; f < 2; ++f) {
                const f32x16 v = acc[mt][f];
                float pm0 = fmaxf(fmaxf(fmaxf(v[0], v[1]), fmaxf(v[2], v[3])),
                                  fmaxf(fmaxf(v[4], v[5]), fmaxf(v[6], v[7])));
                float pm1 = fmaxf(fmaxf(fmaxf(v[8], v[9]), fmaxf(v[10], v[11])),
                                  fmaxf(fmaxf(v[12], v[13]), fmaxf(v[14], v[15])));
                float om0 = fmaxf(pm0, __shfl_xor(pm0, 32));
                float om1 = fmaxf(pm1, __shfl_xor(pm1, 32));
                float e0 = ((fast_exp2(v[0] - om0) + fast_exp2(v[1] - om0))
                          + (fast_exp2(v[2] - om0) + fast_exp2(v[3] - om0)))
                         + ((fast_exp2(v[4] - om0) + fast_exp2(v[5] - om0))
                          + (fast_exp2(v[6] - om0) + fast_exp2(v[7] - om0)));
                float e1 = ((fast_exp2(v[8]  - om1) + fast_exp2(v[9]  - om1))
                          + (fast_exp2(v[10] - om1) + fast_exp2(v[11] - om1)))
                         + ((fast_exp2(v[12] - om1) + fast_exp2(v[13] - om1))
                          + (fast_exp2(v[14] - om1) + fast_exp2(v[15] - om1)));
                float s0 = e0 + __shfl_xor(e0, 32);
                float s1 = e1 + __shfl_xor(e1, 32);
                float pos0 = __shfl_xor(v[7], 32);
                float pos1 = v[15];
                const float pos = hi ? pos1 : pos0;
                const float om  = hi ? om1  : om0;
                const float s   = hi ? s1   : s0;
                const int i = mt * 64 + f * 32 + l31;
                trans[i][jc] = (pos - om - fast_log2(s)) * LN2;
            }
        }

        __syncthreads();

        {
            const int i = tid;
            float r[8];
            #pragma unroll
            for (int c = 0; c < 8; ++c) r[c] = trans[i][c];
            float* dst = out + ((size_t)b * SS + i) * SS + tile_n * 8;
            *(f32x4*)(dst)     = *(f32x4*)(r);
            *(f32x4*)(dst + 4) = *(f32x4*)(r + 4);
        }

        if (t == 0) __syncthreads();
    }
}

extern "C" void kernel_launch(void* const* d_in, const int* in_sizes, int n_in,
                              void* d_out, int out_size, void* d_ws, size_t ws_size,
                              hipStream_t stream) {
    const float* latent  = (const float*)d_in[0];
    const int*   labels  = (const int*)d_in[1];
    const int*   samples = (const int*)d_in[2];
    const float* embed   = (const float*)d_in[3];
    float* out = (float*)d_out;

    if (ws_size >= (size_t)NLAT * 2) {
        ushort_t* ws_lat = (ushort_t*)d_ws;
        convert_lat_kernel<<<(NCHUNK_LAT + 255) / 256, 256, 0, stream>>>(
            latent, ws_lat);
        neg_loss_main<<<dim3(32, 32), dim3(256), 0, stream>>>(
            ws_lat, labels, samples, embed, out);
    } else {
        neg_loss_fused<<<dim3(512), dim3(256), 0, stream>>>(
            latent, labels, samples, embed, out);
    }
}

// Round 15
// 33.999 us; speedup vs baseline: 1.0309x; 1.0309x over previous
//
#include <hip/hip_runtime.h>
#include <hip/hip_bf16.h>
#include <math.h>

#define BB 32
#define SS 256
#define DD 128
#define KK 16
#define VV 50000
#define SK (SS*KK)     // 4096
#define LOG2E 1.44269504f
#define LN2   0.69314718f

typedef __attribute__((ext_vector_type(8))) short bf16x8;
typedef __attribute__((ext_vector_type(4))) float f32x4;
typedef __attribute__((ext_vector_type(16))) float f32x16;
typedef unsigned short ushort_t;

static __device__ __forceinline__ short f2bf(float f) {
    __hip_bfloat16 h = __float2bfloat16(f);
    return *(short*)&h;
}

static __device__ __forceinline__ float fast_exp2(float x) {
    float r; asm("v_exp_f32 %0, %1" : "=v"(r) : "v"(x)); return r;
}
static __device__ __forceinline__ float fast_log2(float x) {
    float r; asm("v_log_f32 %0, %1" : "=v"(r) : "v"(x)); return r;
}

// byte offset of (row, d) in the [256][128] bf16 LDS tile, XOR-swizzled:
// 16B-chunk q -> q ^ (row & 15). Conflict-free on b128 frag reads (measured 0).
static __device__ __forceinline__ int lds_off(int row, int d) {
    return row * 256 + ((d * 2) ^ ((row & 15) << 4));
}

static __device__ __forceinline__ void gload_lds16(const void* g, void* lds) {
    __builtin_amdgcn_global_load_lds(
        (const __attribute__((address_space(1))) unsigned int*)g,
        (__attribute__((address_space(3))) unsigned int*)lds, 16, 0, 0);
}

#define NLAT (BB*SS*DD)       // 1,048,576
#define NCHUNK_LAT (NLAT/8)   // 131,072

// ---------------- K1: latent fp32 -> bf16 * LOG2E ---------------------------
__global__ __launch_bounds__(256)
void convert_lat_kernel(const float* __restrict__ latent,
                        ushort_t* __restrict__ ws_lat)
{
    int i = blockIdx.x * 256 + threadIdx.x;
    if (i >= NCHUNK_LAT) return;
    const float* src = latent + (size_t)i * 8;
    float f[8];
    *(f32x4*)(f + 0) = ((const f32x4*)src)[0];
    *(f32x4*)(f + 4) = ((const f32x4*)src)[1];
    short o[8];
    #pragma unroll
    for (int e = 0; e < 8; ++e) o[e] = f2bf(f[e] * LOG2E);
    *(bf16x8*)(ws_lat + (size_t)i * 8) = *(bf16x8*)o;
}

// ---------------- K2: persistent main (R13 structure, stripped) -------------
// grid 512 = 2 blocks/CU. Block: b = p>>4, two n-tiles.
// Issue BOTH tile gathers + 16x gload_lds (A: 256 bf16 rows, 64 KB) ->
// ONE barrier -> tile0 {av cvt, MFMA(setprio), LSE, direct stores} -> tile1.
// No trans LDS, no further barriers (ldsA read-only after stage).
__global__ __launch_bounds__(256, 2)
void neg_loss_persist(const ushort_t* __restrict__ lat_bf,  // [B,S,D] bf16*log2e
                      const int*   __restrict__ labels,     // [B,S]
                      const int*   __restrict__ samples,    // [B,S*(K-1)]
                      const float* __restrict__ embed,      // [V,D] fp32
                      float* __restrict__ out)              // [B,S,S]
{
    __shared__ char ldsA[SS * 256];   // 64 KB

    const int p     = blockIdx.x;
    const int b     = p >> 4;
    const int npair = p & 15;
    const int tid   = threadIdx.x;
    const int wave  = tid >> 6;
    const int lane  = tid & 63;
    const int q     = lane & 15;
    const int sub   = lane >> 4;
    const int l31   = lane & 31;
    const int hi    = lane >> 5;

    // ---- candidate indices for both tiles ----
    const int rB  = wave * 32 + l31;
    const int gc0 = (npair * 2) * 128 + rB;
    const int gc1 = gc0 + 128;
    const int j0i = gc0 >> 4, k0i = gc0 & 15;
    const int j1i = gc1 >> 4, k1i = gc1 & 15;
    const int idx0 = (k0i < 15)
        ? samples[(size_t)b * (SS * (KK - 1)) + j0i * (KK - 1) + k0i]
        : labels[b * SS + j0i];
    const int idx1 = (k1i < 15)
        ? samples[(size_t)b * (SS * (KK - 1)) + j1i * (KK - 1) + k1i]
        : labels[b * SS + j1i];

    // ---- issue BOTH gathers up front (max MLP at the single drain) ----
    f32x4 fbA[16], fbB[16];
    {
        const float* rowp0 = embed + (size_t)idx0 * DD + hi * 8;
        const float* rowp1 = embed + (size_t)idx1 * DD + hi * 8;
        #pragma unroll
        for (int ks = 0; ks < 8; ++ks) {
            fbA[2 * ks]     = *(const f32x4*)(rowp0 + ks * 16);
            fbA[2 * ks + 1] = *(const f32x4*)(rowp0 + ks * 16 + 4);
        }
        #pragma unroll
        for (int ks = 0; ks < 8; ++ks) {
            fbB[2 * ks]     = *(const f32x4*)(rowp1 + ks * 16);
            fbB[2 * ks + 1] = *(const f32x4*)(rowp1 + ks * 16 + 4);
        }
    }

    // ---- A-stage via DMA: 256 bf16 rows, pre-swizzled source ----
    #pragma unroll
    for (int t = 0; t < 16; ++t) {
        const int r0 = wave * 64 + t * 4;
        const int r  = r0 + sub;
        const ushort_t* src = lat_bf + ((size_t)(b * SS + r) * DD)
                                     + ((q ^ (r & 15)) << 3);
        gload_lds16(src, ldsA + r0 * 256);
    }

    __syncthreads();   // single drain: A in LDS, fbA+fbB in regs

    // ================= two tiles =================
    #pragma unroll
    for (int t = 0; t < 2; ++t) {
        const int jcol = (npair * 2 + t) * 8 + wave * 2 + hi;

        bf16x8 av[8];
        #pragma unroll
        for (int ks = 0; ks < 8; ++ks) {
            const f32x4 lo  = t ? fbB[2 * ks]     : fbA[2 * ks];
            const f32x4 hi4 = t ? fbB[2 * ks + 1] : fbA[2 * ks + 1];
            short t8[8];
            #pragma unroll
            for (int e = 0; e < 4; ++e) t8[e]     = f2bf(lo[e]);
            #pragma unroll
            for (int e = 0; e < 4; ++e) t8[4 + e] = f2bf(hi4[e]);
            av[ks] = *(bf16x8*)t8;
        }

        // ---- MFMA 32x32x16, swapped: D[row=cand][col=lat(scaled)] ----
        f32x16 acc[4][2] = {};
        __builtin_amdgcn_s_setprio(1);
        #pragma unroll
        for (int ks = 0; ks < 8; ++ks) {
            const int d = ks * 16 + hi * 8;
            #pragma unroll
            for (int mt = 0; mt < 4; ++mt) {
                bf16x8 bv0 = *(const bf16x8*)(ldsA + lds_off(mt * 64 + l31, d));
                bf16x8 bv1 = *(const bf16x8*)(ldsA + lds_off(mt * 64 + 32 + l31, d));
                acc[mt][0] = __builtin_amdgcn_mfma_f32_32x32x16_bf16(av[ks], bv0, acc[mt][0], 0, 0, 0);
                acc[mt][1] = __builtin_amdgcn_mfma_f32_32x32x16_bf16(av[ks], bv1, acc[mt][1], 0, 0, 0);
            }
        }
        __builtin_amdgcn_s_setprio(0);

        // ---- fused LSE (base-2), direct per-lane stores ----
        // D rows/lane: (reg&3)+8*(reg>>2)+4*hi; group0 = regs0-7, group1 = 8-15.
        #pragma unroll
        for (int mt = 0; mt < 4; ++mt) {
            #pragma unroll
            for (int f = 0; f < 2; ++f) {
                const f32x16 v = acc[mt][f];
                float pm0 = fmaxf(fmaxf(fmaxf(v[0], v[1]), fmaxf(v[2], v[3])),
                                  fmaxf(fmaxf(v[4], v[5]), fmaxf(v[6], v[7])));
                float pm1 = fmaxf(fmaxf(fmaxf(v[8], v[9]), fmaxf(v[10], v[11])),
                                  fmaxf(fmaxf(v[12], v[13]), fmaxf(v[14], v[15])));
                float om0 = fmaxf(pm0, __shfl_xor(pm0, 32));
                float om1 = fmaxf(pm1, __shfl_xor(pm1, 32));
                float e0 = ((fast_exp2(v[0] - om0) + fast_exp2(v[1] - om0))
                          + (fast_exp2(v[2] - om0) + fast_exp2(v[3] - om0)))
                         + ((fast_exp2(v[4] - om0) + fast_exp2(v[5] - om0))
                          + (fast_exp2(v[6] - om0) + fast_exp2(v[7] - om0)));
                float e1 = ((fast_exp2(v[8]  - om1) + fast_exp2(v[9]  - om1))
                          + (fast_exp2(v[10] - om1) + fast_exp2(v[11] - om1)))
                         + ((fast_exp2(v[12] - om1) + fast_exp2(v[13] - om1))
                          + (fast_exp2(v[14] - om1) + fast_exp2(v[15] - om1)));
                float s0 = e0 + __shfl_xor(e0, 32);
                float s1 = e1 + __shfl_xor(e1, 32);
                float pos0 = __shfl_xor(v[7], 32);  // hi=0 lanes get cand row 15
                float pos1 = v[15];                 // hi=1 lanes hold cand row 31
                const float pos = hi ? pos1 : pos0;
                const float om  = hi ? om1  : om0;
                const float s   = hi ? s1   : s0;
                const int i = mt * 64 + f * 32 + l31;
                out[((size_t)b * SS + i) * SS + jcol]
                    = (pos - om - fast_log2(s)) * LN2;
            }
        }
    }
}

// ---------------- fallback: R11-style fused kernel (no ws) ------------------
__global__ __launch_bounds__(256, 2)
void neg_loss_fused(const float* __restrict__ latent,
                    const int*   __restrict__ labels,
                    const int*   __restrict__ samples,
                    const float* __restrict__ embed,
                    float* __restrict__ out)
{
    __shared__ char ldsA[SS * 256];

    const int p     = blockIdx.x;
    const int b     = p >> 4;
    const int npair = p & 15;
    const int tid   = threadIdx.x;
    const int wave  = tid >> 6;
    const int lane  = tid & 63;
    const int l31   = lane & 31;
    const int hi    = lane >> 5;

    const int rB  = wave * 32 + l31;
    const int gc0 = (npair * 2) * 128 + rB;
    const int gc1 = gc0 + 128;
    const int j0i = gc0 >> 4, k0i = gc0 & 15;
    const int j1i = gc1 >> 4, k1i = gc1 & 15;
    const int idx0 = (k0i < 15)
        ? samples[(size_t)b * (SS * (KK - 1)) + j0i * (KK - 1) + k0i]
        : labels[b * SS + j0i];
    const int idx1 = (k1i < 15)
        ? samples[(size_t)b * (SS * (KK - 1)) + j1i * (KK - 1) + k1i]
        : labels[b * SS + j1i];

    f32x4 fbA[16], fbB[16];
    {
        const float* rowp0 = embed + (size_t)idx0 * DD + hi * 8;
        const float* rowp1 = embed + (size_t)idx1 * DD + hi * 8;
        #pragma unroll
        for (int ks = 0; ks < 8; ++ks) {
            fbA[2 * ks]     = *(const f32x4*)(rowp0 + ks * 16);
            fbA[2 * ks + 1] = *(const f32x4*)(rowp0 + ks * 16 + 4);
        }
        #pragma unroll
        for (int ks = 0; ks < 8; ++ks) {
            fbB[2 * ks]     = *(const f32x4*)(rowp1 + ks * 16);
            fbB[2 * ks + 1] = *(const f32x4*)(rowp1 + ks * 16 + 4);
        }
    }

    #pragma unroll
    for (int pr = 0; pr < 4; ++pr) {
        const int r  = pr * 64 + (tid >> 2);
        const int d0 = (tid & 3) * 32;
        const float* src = latent + ((size_t)b * SS + r) * DD + d0;
        f32x4 f[8];
        #pragma unroll
        for (int c = 0; c < 8; ++c) f[c] = *(const f32x4*)(src + 4 * c);
        short o[32];
        #pragma unroll
        for (int c = 0; c < 8; ++c)
            #pragma unroll
            for (int e = 0; e < 4; ++e)
                o[4 * c + e] = f2bf(f[c][e] * LOG2E);
        #pragma unroll
        for (int c = 0; c < 4; ++c)
            *(bf16x8*)(ldsA + lds_off(r, d0 + 8 * c)) = *(bf16x8*)(o + 8 * c);
    }

    __syncthreads();

    #pragma unroll
    for (int t = 0; t < 2; ++t) {
        const int jcol = (npair * 2 + t) * 8 + wave * 2 + hi;

        bf16x8 av[8];
        #pragma unroll
        for (int ks = 0; ks < 8; ++ks) {
            const f32x4 lo  = t ? fbB[2 * ks]     : fbA[2 * ks];
            const f32x4 hi4 = t ? fbB[2 * ks + 1] : fbA[2 * ks + 1];
            short t8[8];
            #pragma unroll
            for (int e = 0; e < 4; ++e) t8[e]     = f2bf(lo[e]);
            #pragma unroll
            for (int e = 0; e < 4; ++e) t8[4 + e] = f2bf(hi4[e]);
            av[ks] = *(bf16x8*)t8;
        }

        f32x16 acc[4][2] = {};
        __builtin_amdgcn_s_setprio(1);
        #pragma unroll
        for (int ks = 0; ks < 8; ++ks) {
            const int d = ks * 16 + hi * 8;
            #pragma unroll
            for (int mt = 0; mt < 4; ++mt) {
                bf16x8 bv0 = *(const bf16x8*)(ldsA + lds_off(mt * 64 + l31, d));
                bf16x8 bv1 = *(const bf16x8*)(ldsA + lds_off(mt * 64 + 32 + l31, d));
                acc[mt][0] = __builtin_amdgcn_mfma_f32_32x32x16_bf16(av[ks], bv0, acc[mt][0], 0, 0, 0);
                acc[mt][1] = __builtin_amdgcn_mfma_f32_32x32x16_bf16(av[ks], bv1, acc[mt][1], 0, 0, 0);
            }
        }
        __builtin_amdgcn_s_setprio(0);

        #pragma unroll
        for (int mt = 0; mt < 4; ++mt) {
            #pragma unroll
            for (int f = 0; f < 2; ++f) {
                const f32x16 v = acc[mt][f];
                float pm0 = fmaxf(fmaxf(fmaxf(v[0], v[1]), fmaxf(v[2], v[3])),
                                  fmaxf(fmaxf(v[4], v[5]), fmaxf(v[6], v[7])));
                float pm1 = fmaxf(fmaxf(fmaxf(v[8], v[9]), fmaxf(v[10], v[11])),
                                  fmaxf(fmaxf(v[12], v[13]), fmaxf(v[14], v[15])));
                float om0 = fmaxf(pm0, __shfl_xor(pm0, 32));
                float om1 = fmaxf(pm1, __shfl_xor(pm1, 32));
                float e0 = ((fast_exp2(v[0] - om0) + fast_exp2(v[1] - om0))
                          + (fast_exp2(v[2] - om0) + fast_exp2(v[3] - om0)))
                         + ((fast_exp2(v[4] - om0) + fast_exp2(v[5] - om0))
                          + (fast_exp2(v[6] - om0) + fast_exp2(v[7] - om0)));
                float e1 = ((fast_exp2(v[8]  - om1) + fast_exp2(v[9]  - om1))
                          + (fast_exp2(v[10] - om1) + fast_exp2(v[11] - om1)))
                         + ((fast_exp2(v[12] - om1) + fast_exp2(v[13] - om1))
                          + (fast_exp2(v[14] - om1) + fast_exp2(v[15] - om1)));
                float s0 = e0 + __shfl_xor(e0, 32);
                float s1 = e1 + __shfl_xor(e1, 32);
                float pos0 = __shfl_xor(v[7], 32);
                float pos1 = v[15];
                const float pos = hi ? pos1 : pos0;
                const float om  = hi ? om1  : om0;
                const float s   = hi ? s1   : s0;
                const int i = mt * 64 + f * 32 + l31;
                out[((size_t)b * SS + i) * SS + jcol]
                    = (pos - om - fast_log2(s)) * LN2;
            }
        }
    }
}

extern "C" void kernel_launch(void* const* d_in, const int* in_sizes, int n_in,
                              void* d_out, int out_size, void* d_ws, size_t ws_size,
                              hipStream_t stream) {
    const float* latent  = (const float*)d_in[0];
    const int*   labels  = (const int*)d_in[1];
    const int*   samples = (const int*)d_in[2];
    const float* embed   = (const float*)d_in[3];
    float* out = (float*)d_out;

    if (ws_size >= (size_t)NLAT * 2) {
        ushort_t* ws_lat = (ushort_t*)d_ws;
        convert_lat_kernel<<<(NCHUNK_LAT + 255) / 256, 256, 0, stream>>>(
            latent, ws_lat);
        neg_loss_persist<<<dim3(512), dim3(256), 0, stream>>>(
            ws_lat, labels, samples, embed, out);
    } else {
        neg_loss_fused<<<dim3(512), dim3(256), 0, stream>>>(
            latent, labels, samples, embed, out);
    }
}

// Round 16
// 32.332 us; speedup vs baseline: 1.0840x; 1.0516x over previous
//
#include <hip/hip_runtime.h>
#include <hip/hip_bf16.h>
#include <math.h>

#define BB 32
#define SS 256
#define DD 128
#define KK 16
#define VV 50000
#define SK (SS*KK)     // 4096
#define LOG2E 1.44269504f
#define LN2   0.69314718f

typedef __attribute__((ext_vector_type(8))) short bf16x8;
typedef __attribute__((ext_vector_type(4))) float f32x4;
typedef __attribute__((ext_vector_type(16))) float f32x16;
typedef unsigned short ushort_t;

static __device__ __forceinline__ short f2bf(float f) {
    __hip_bfloat16 h = __float2bfloat16(f);
    return *(short*)&h;
}

static __device__ __forceinline__ float fast_exp2(float x) {
    float r; asm("v_exp_f32 %0, %1" : "=v"(r) : "v"(x)); return r;
}
static __device__ __forceinline__ float fast_log2(float x) {
    float r; asm("v_log_f32 %0, %1" : "=v"(r) : "v"(x)); return r;
}

// byte offset of (row, d) in the [256][128] bf16 LDS tile, XOR-swizzled:
// 16B-chunk q -> q ^ (row & 15). Conflict-free on frag reads (R10: 0 conflicts).
static __device__ __forceinline__ int lds_off(int row, int d) {
    return row * 256 + ((d * 2) ^ ((row & 15) << 4));
}

static __device__ __forceinline__ void gload_lds16(const void* g, void* lds) {
    __builtin_amdgcn_global_load_lds(
        (const __attribute__((address_space(1))) unsigned int*)g,
        (__attribute__((address_space(3))) unsigned int*)lds, 16, 0, 0);
}

#define NLAT (BB*SS*DD)       // 1,048,576
#define NCHUNK_LAT (NLAT/8)   // 131,072

// ---------------- K1: latent fp32 -> bf16 * LOG2E ---------------------------
__global__ __launch_bounds__(256)
void convert_lat_kernel(const float* __restrict__ latent,
                        ushort_t* __restrict__ ws_lat)
{
    int i = blockIdx.x * 256 + threadIdx.x;
    if (i >= NCHUNK_LAT) return;
    const float* src = latent + (size_t)i * 8;
    float f[8];
    *(f32x4*)(f + 0) = ((const f32x4*)src)[0];
    *(f32x4*)(f + 4) = ((const f32x4*)src)[1];
    short o[8];
    #pragma unroll
    for (int e = 0; e < 8; ++e) o[e] = f2bf(f[e] * LOG2E);
    *(bf16x8*)(ws_lat + (size_t)i * 8) = *(bf16x8*)o;
}

// ---------------- K2: persistent main (R13 structure — measured best) -------
// grid 512 = 2 blocks/CU resident. Block: b = p>>4, two n-tiles (npair).
// Issue fb(tile0) gather -> issue 16x gload_lds (A: 256 bf16 rows, 64 KB)
// -> barrier (single vmcnt drain) -> issue fb(tile1) -> compute tile0 -> tile1.
__global__ __launch_bounds__(256, 2)
void neg_loss_persist(const ushort_t* __restrict__ lat_bf,  // [B,S,D] bf16*log2e
                      const int*   __restrict__ labels,     // [B,S]
                      const int*   __restrict__ samples,    // [B,S*(K-1)]
                      const float* __restrict__ embed,      // [V,D] fp32
                      float* __restrict__ out)              // [B,S,S]
{
    __shared__ char  ldsA[SS * 256];   // 64 KB
    __shared__ float trans[256][9];    // 9 KB

    const int p     = blockIdx.x;
    const int b     = p >> 4;
    const int npair = p & 15;
    const int tid   = threadIdx.x;
    const int wave  = tid >> 6;
    const int lane  = tid & 63;
    const int q     = lane & 15;
    const int sub   = lane >> 4;
    const int l31   = lane & 31;
    const int hi    = lane >> 5;

    // ---- candidate indices for both tiles ----
    const int rB  = wave * 32 + l31;
    const int gc0 = (npair * 2) * 128 + rB;
    const int gc1 = gc0 + 128;
    const int j0i = gc0 >> 4, k0i = gc0 & 15;
    const int j1i = gc1 >> 4, k1i = gc1 & 15;
    const int idx0 = (k0i < 15)
        ? samples[(size_t)b * (SS * (KK - 1)) + j0i * (KK - 1) + k0i]
        : labels[b * SS + j0i];
    const int idx1 = (k1i < 15)
        ? samples[(size_t)b * (SS * (KK - 1)) + j1i * (KK - 1) + k1i]
        : labels[b * SS + j1i];

    // ---- issue tile0 gather FIRST ----
    f32x4 fbA[16];
    {
        const float* rowp = embed + (size_t)idx0 * DD + hi * 8;
        #pragma unroll
        for (int ks = 0; ks < 8; ++ks) {
            fbA[2 * ks]     = *(const f32x4*)(rowp + ks * 16);
            fbA[2 * ks + 1] = *(const f32x4*)(rowp + ks * 16 + 4);
        }
    }

    // ---- A-stage via DMA: 256 bf16 rows, pre-swizzled source ----
    #pragma unroll
    for (int t = 0; t < 16; ++t) {
        const int r0 = wave * 64 + t * 4;
        const int r  = r0 + sub;
        const ushort_t* src = lat_bf + ((size_t)(b * SS + r) * DD)
                                     + ((q ^ (r & 15)) << 3);
        gload_lds16(src, ldsA + r0 * 256);
    }

    __syncthreads();   // drains vmcnt: A in LDS, fbA in regs

    // ---- issue tile1 gather now (hidden under tile0 compute) ----
    f32x4 fbB[16];
    {
        const float* rowp = embed + (size_t)idx1 * DD + hi * 8;
        #pragma unroll
        for (int ks = 0; ks < 8; ++ks) {
            fbB[2 * ks]     = *(const f32x4*)(rowp + ks * 16);
            fbB[2 * ks + 1] = *(const f32x4*)(rowp + ks * 16 + 4);
        }
    }

    // ================= two tiles =================
    #pragma unroll
    for (int t = 0; t < 2; ++t) {
        const int tile_n = npair * 2 + t;
        const int jc     = wave * 2 + hi;

        bf16x8 av[8];
        #pragma unroll
        for (int ks = 0; ks < 8; ++ks) {
            const f32x4 lo  = t ? fbB[2 * ks]     : fbA[2 * ks];
            const f32x4 hi4 = t ? fbB[2 * ks + 1] : fbA[2 * ks + 1];
            short t8[8];
            #pragma unroll
            for (int e = 0; e < 4; ++e) t8[e]     = f2bf(lo[e]);
            #pragma unroll
            for (int e = 0; e < 4; ++e) t8[4 + e] = f2bf(hi4[e]);
            av[ks] = *(bf16x8*)t8;
        }

        // ---- MFMA 32x32x16, swapped: D[row=cand][col=lat(scaled)] ----
        f32x16 acc[4][2] = {};
        #pragma unroll
        for (int ks = 0; ks < 8; ++ks) {
            const int d = ks * 16 + hi * 8;
            #pragma unroll
            for (int mt = 0; mt < 4; ++mt) {
                bf16x8 bv0 = *(const bf16x8*)(ldsA + lds_off(mt * 64 + l31, d));
                bf16x8 bv1 = *(const bf16x8*)(ldsA + lds_off(mt * 64 + 32 + l31, d));
                acc[mt][0] = __builtin_amdgcn_mfma_f32_32x32x16_bf16(av[ks], bv0, acc[mt][0], 0, 0, 0);
                acc[mt][1] = __builtin_amdgcn_mfma_f32_32x32x16_bf16(av[ks], bv1, acc[mt][1], 0, 0, 0);
            }
        }

        // ---- fused LSE (base-2) -> trans ----
        #pragma unroll
        for (int mt = 0; mt < 4; ++mt) {
            #pragma unroll
            for (int f = 0; f < 2; ++f) {
                const f32x16 v = acc[mt][f];
                float pm0 = fmaxf(fmaxf(fmaxf(v[0], v[1]), fmaxf(v[2], v[3])),
                                  fmaxf(fmaxf(v[4], v[5]), fmaxf(v[6], v[7])));
                float pm1 = fmaxf(fmaxf(fmaxf(v[8], v[9]), fmaxf(v[10], v[11])),
                                  fmaxf(fmaxf(v[12], v[13]), fmaxf(v[14], v[15])));
                float om0 = fmaxf(pm0, __shfl_xor(pm0, 32));
                float om1 = fmaxf(pm1, __shfl_xor(pm1, 32));
                float e0 = ((fast_exp2(v[0] - om0) + fast_exp2(v[1] - om0))
                          + (fast_exp2(v[2] - om0) + fast_exp2(v[3] - om0)))
                         + ((fast_exp2(v[4] - om0) + fast_exp2(v[5] - om0))
                          + (fast_exp2(v[6] - om0) + fast_exp2(v[7] - om0)));
                float e1 = ((fast_exp2(v[8]  - om1) + fast_exp2(v[9]  - om1))
                          + (fast_exp2(v[10] - om1) + fast_exp2(v[11] - om1)))
                         + ((fast_exp2(v[12] - om1) + fast_exp2(v[13] - om1))
                          + (fast_exp2(v[14] - om1) + fast_exp2(v[15] - om1)));
                float s0 = e0 + __shfl_xor(e0, 32);
                float s1 = e1 + __shfl_xor(e1, 32);
                float pos0 = __shfl_xor(v[7], 32);  // hi=0 lanes get cand row 15
                float pos1 = v[15];                 // hi=1 lanes hold cand row 31
                const float pos = hi ? pos1 : pos0;
                const float om  = hi ? om1  : om0;
                const float s   = hi ? s1   : s0;
                const int i = mt * 64 + f * 32 + l31;
                trans[i][jc] = (pos - om - fast_log2(s)) * LN2;
            }
        }

        __syncthreads();   // trans complete

        // ---- store: thread i writes out[b][i][tile_n*8 .. +8) as 2x16B ----
        {
            const int i = tid;
            float r[8];
            #pragma unroll
            for (int c = 0; c < 8; ++c) r[c] = trans[i][c];
            float* dst = out + ((size_t)b * SS + i) * SS + tile_n * 8;
            *(f32x4*)(dst)     = *(f32x4*)(r);
            *(f32x4*)(dst + 4) = *(f32x4*)(r + 4);
        }

        if (t == 0) __syncthreads();   // protect trans before tile1 overwrite
    }
}

// ---------------- fallback: R11 fused kernel (no ws needed) -----------------
__global__ __launch_bounds__(256, 2)
void neg_loss_fused(const float* __restrict__ latent,
                    const int*   __restrict__ labels,
                    const int*   __restrict__ samples,
                    const float* __restrict__ embed,
                    float* __restrict__ out)
{
    __shared__ char  ldsA[SS * 256];
    __shared__ float trans[256][9];

    const int p     = blockIdx.x;
    const int b     = p >> 4;
    const int npair = p & 15;
    const int tid   = threadIdx.x;
    const int wave  = tid >> 6;
    const int lane  = tid & 63;
    const int l31   = lane & 31;
    const int hi    = lane >> 5;

    const int rB  = wave * 32 + l31;
    const int gc0 = (npair * 2) * 128 + rB;
    const int gc1 = gc0 + 128;
    const int j0i = gc0 >> 4, k0i = gc0 & 15;
    const int j1i = gc1 >> 4, k1i = gc1 & 15;
    const int idx0 = (k0i < 15)
        ? samples[(size_t)b * (SS * (KK - 1)) + j0i * (KK - 1) + k0i]
        : labels[b * SS + j0i];
    const int idx1 = (k1i < 15)
        ? samples[(size_t)b * (SS * (KK - 1)) + j1i * (KK - 1) + k1i]
        : labels[b * SS + j1i];

    f32x4 fbA[16];
    {
        const float* rowp = embed + (size_t)idx0 * DD + hi * 8;
        #pragma unroll
        for (int ks = 0; ks < 8; ++ks) {
            fbA[2 * ks]     = *(const f32x4*)(rowp + ks * 16);
            fbA[2 * ks + 1] = *(const f32x4*)(rowp + ks * 16 + 4);
        }
    }

    #pragma unroll
    for (int pr = 0; pr < 4; ++pr) {
        const int r  = pr * 64 + (tid >> 2);
        const int d0 = (tid & 3) * 32;
        const float* src = latent + ((size_t)b * SS + r) * DD + d0;
        f32x4 f[8];
        #pragma unroll
        for (int c = 0; c < 8; ++c) f[c] = *(const f32x4*)(src + 4 * c);
        short o[32];
        #pragma unroll
        for (int c = 0; c < 8; ++c)
            #pragma unroll
            for (int e = 0; e < 4; ++e)
                o[4 * c + e] = f2bf(f[c][e] * LOG2E);
        #pragma unroll
        for (int c = 0; c < 4; ++c)
            *(bf16x8*)(ldsA + lds_off(r, d0 + 8 * c)) = *(bf16x8*)(o + 8 * c);
    }

    __syncthreads();

    f32x4 fbB[16];
    {
        const float* rowp = embed + (size_t)idx1 * DD + hi * 8;
        #pragma unroll
        for (int ks = 0; ks < 8; ++ks) {
            fbB[2 * ks]     = *(const f32x4*)(rowp + ks * 16);
            fbB[2 * ks + 1] = *(const f32x4*)(rowp + ks * 16 + 4);
        }
    }

    #pragma unroll
    for (int t = 0; t < 2; ++t) {
        const int tile_n = npair * 2 + t;
        const int jc     = wave * 2 + hi;

        bf16x8 av[8];
        #pragma unroll
        for (int ks = 0; ks < 8; ++ks) {
            const f32x4 lo  = t ? fbB[2 * ks]     : fbA[2 * ks];
            const f32x4 hi4 = t ? fbB[2 * ks + 1] : fbA[2 * ks + 1];
            short t8[8];
            #pragma unroll
            for (int e = 0; e < 4; ++e) t8[e]     = f2bf(lo[e]);
            #pragma unroll
            for (int e = 0; e < 4; ++e) t8[4 + e] = f2bf(hi4[e]);
            av[ks] = *(bf16x8*)t8;
        }

        f32x16 acc[4][2] = {};
        #pragma unroll
        for (int ks = 0; ks < 8; ++ks) {
            const int d = ks * 16 + hi * 8;
            #pragma unroll
            for (int mt = 0; mt < 4; ++mt) {
                bf16x8 bv0 = *(const bf16x8*)(ldsA + lds_off(mt * 64 + l31, d));
                bf16x8 bv1 = *(const bf16x8*)(ldsA + lds_off(mt * 64 + 32 + l31, d));
                acc[mt][0] = __builtin_amdgcn_mfma_f32_32x32x16_bf16(av[ks], bv0, acc[mt][0], 0, 0, 0);
                acc[mt][1] = __builtin_amdgcn_mfma_f32_32x32x16_bf16(av[ks], bv1, acc[mt][1], 0, 0, 0);
            }
        }

        #pragma unroll
        for (int mt = 0; mt < 4; ++mt) {
            #pragma unroll
            for (int f = 0; f < 2; ++f) {
                const f32x16 v = acc[mt][f];
                float pm0 = fmaxf(fmaxf(fmaxf(v[0], v[1]), fmaxf(v[2], v[3])),
                                  fmaxf(fmaxf(v[4], v[5]), fmaxf(v[6], v[7])));
                float pm1 = fmaxf(fmaxf(fmaxf(v[8], v[9]), fmaxf(v[10], v[11])),
                                  fmaxf(fmaxf(v[12], v[13]), fmaxf(v[14], v[15])));
                float om0 = fmaxf(pm0, __shfl_xor(pm0, 32));
                float om1 = fmaxf(pm1, __shfl_xor(pm1, 32));
                float e0 = ((fast_exp2(v[0] - om0) + fast_exp2(v[1] - om0))
                          + (fast_exp2(v[2] - om0) + fast_exp2(v[3] - om0)))
                         + ((fast_exp2(v[4] - om0) + fast_exp2(v[5] - om0))
                          + (fast_exp2(v[6] - om0) + fast_exp2(v[7] - om0)));
                float e1 = ((fast_exp2(v[8]  - om1) + fast_exp2(v[9]  - om1))
                          + (fast_exp2(v[10] - om1) + fast_exp2(v[11] - om1)))
                         + ((fast_exp2(v[12] - om1) + fast_exp2(v[13] - om1))
                          + (fast_exp2(v[14] - om1) + fast_exp2(v[15] - om1)));
                float s0 = e0 + __shfl_xor(e0, 32);
                float s1 = e1 + __shfl_xor(e1, 32);
                float pos0 = __shfl_xor(v[7], 32);
                float pos1 = v[15];
                const float pos = hi ? pos1 : pos0;
                const float om  = hi ? om1  : om0;
                const float s   = hi ? s1   : s0;
                const int i = mt * 64 + f * 32 + l31;
                trans[i][jc] = (pos - om - fast_log2(s)) * LN2;
            }
        }

        __syncthreads();

        {
            const int i = tid;
            float r[8];
            #pragma unroll
            for (int c = 0; c < 8; ++c) r[c] = trans[i][c];
            float* dst = out + ((size_t)b * SS + i) * SS + tile_n * 8;
            *(f32x4*)(dst)     = *(f32x4*)(r);
            *(f32x4*)(dst + 4) = *(f32x4*)(r + 4);
        }

        if (t == 0) __syncthreads();
    }
}

extern "C" void kernel_launch(void* const* d_in, const int* in_sizes, int n_in,
                              void* d_out, int out_size, void* d_ws, size_t ws_size,
                              hipStream_t stream) {
    const float* latent  = (const float*)d_in[0];
    const int*   labels  = (const int*)d_in[1];
    const int*   samples = (const int*)d_in[2];
    const float* embed   = (const float*)d_in[3];
    float* out = (float*)d_out;

    if (ws_size >= (size_t)NLAT * 2) {
        ushort_t* ws_lat = (ushort_t*)d_ws;
        convert_lat_kernel<<<(NCHUNK_LAT + 255) / 256, 256, 0, stream>>>(
            latent, ws_lat);
        neg_loss_persist<<<dim3(512), dim3(256), 0, stream>>>(
            ws_lat, labels, samples, embed, out);
    } else {
        neg_loss_fused<<<dim3(512), dim3(256), 0, stream>>>(
            latent, labels, samples, embed, out);
    }
}